// Round 16
// baseline (316.202 us; speedup 1.0000x reference)
//
#include <hip/hip_runtime.h>
#include <hip/hip_bf16.h>
#include <math.h>
#include <stdint.h>

typedef _Float16 f16;
typedef _Float16 f16x8 __attribute__((ext_vector_type(8)));
typedef float f32x16 __attribute__((ext_vector_type(16)));
typedef unsigned long long ull;

#define DIM 256
#define LOSCALE 2048.0f
#define INV_LOSCALE (1.0f/2048.0f)
#define EPS0 0.05f

// B' stream: 4096 codes x 256 depth x {hi,lo}, fragment-major:
// byte offset = col*32768 + s*2048 + t*1024 + lane*16
// (col 0..127 = 32 codes each, k-step s 0..15, t 0:hi 1:lo)
// lane l holds 16B = e[code=col*32+(l&31)][depth=s*16+(l>>5)*8 .. +8]
#define BP_BYTES (4096u*1024u + 98304u)   // 4MB + pad (staging/prefetch overrun)

#define GLOAD16(gp, lp) __builtin_amdgcn_global_load_lds( \
    (const __attribute__((address_space(1))) void*)(gp),  \
    (__attribute__((address_space(3))) void*)(lp), 16, 0, 0)

// monotonic key decode (enc: u ^ ((int(u)>>31)|0x80000000))
__device__ __forceinline__ float dec_key(unsigned k) {
    unsigned u = (k & 0x80000000u) ? (k ^ 0x80000000u) : ~k;
    return __uint_as_float(u);
}

// ---------------------------------------------------------------------------
// pack codebook into fragment-major hi/lo f16 stream
// ---------------------------------------------------------------------------
__global__ void vq_pack2(const float* __restrict__ emb, f16* __restrict__ bp)
{
    int o = blockIdx.x * blockDim.x + threadIdx.x;
    int l = o & 63;
    int b = o >> 6;
    int t   = b & 1;
    int s   = (b >> 1) & 15;
    int col = b >> 5;
    int code  = col * 32 + (l & 31);
    int depth = s * 16 + (l >> 5) * 8;
    const float* gp = emb + (size_t)code * DIM + depth;
    float4 x0 = *(const float4*)gp;
    float4 x1 = *(const float4*)(gp + 4);
    float xs[8] = {x0.x, x0.y, x0.z, x0.w, x1.x, x1.y, x1.z, x1.w};
    f16x8 v;
    #pragma unroll
    for (int j = 0; j < 8; ++j) {
        f16 h = (f16)xs[j];
        v[j] = t ? (f16)((xs[j] - (float)h) * LOSCALE) : h;
    }
    *(f16x8*)(bp + (size_t)o * 8) = v;
}

// ||e||^2 exact + global split-norm maxima (Mel, Meh) via atomicMax
__global__ void vq_e2x(const float* __restrict__ emb, float* __restrict__ e2,
                       unsigned* __restrict__ melmeh)
{
    int k = blockIdx.x;
    int l = threadIdx.x;
    float4 v = ((const float4*)(emb + (size_t)k * DIM))[l];
    float xs[4] = {v.x, v.y, v.z, v.w};
    float s = 0.0f, sh = 0.0f, sl = 0.0f;
    #pragma unroll
    for (int j = 0; j < 4; ++j) {
        float x = xs[j];
        s = fmaf(x, x, s);
        f16 h = (f16)x;
        float hv = (float)h;
        float lv = (float)((f16)((x - hv) * LOSCALE));
        sh = fmaf(hv, hv, sh);
        sl = fmaf(lv, lv, sl);
    }
    #pragma unroll
    for (int off = 32; off; off >>= 1) {
        s  += __shfl_xor(s, off);
        sh += __shfl_xor(sh, off);
        sl += __shfl_xor(sl, off);
    }
    if (l == 0) {
        e2[k] = s;
        atomicMax(&melmeh[0], __float_as_uint(sqrtf(sl)));   // Mel
        atomicMax(&melmeh[1], __float_as_uint(sqrtf(sh)));   // Meh
    }
}

// plain e2 (low fallback path)
__global__ void vq_e2(const float* __restrict__ emb, float* __restrict__ e2) {
    int k = blockIdx.x;
    int l = threadIdx.x;
    float4 v = ((const float4*)(emb + (size_t)k * DIM))[l];
    float s = v.x*v.x + v.y*v.y + v.z*v.z + v.w*v.w;
    #pragma unroll
    for (int off = 32; off; off >>= 1) s += __shfl_xor(s, off);
    if (l == 0) e2[k] = s;
}

__global__ void vq_zero(int* __restrict__ p, int n) {
    int i = blockIdx.x * blockDim.x + threadIdx.x;
    if (i < n) p[i] = 0;
}

// ---------------------------------------------------------------------------
// PASS 1: hi-only scan with (d1,c1,d2) tracking. r10 skeleton:
// 512 thr = 8 waves x 32 rows, one code half; 4 x 32KB units (bh of 2 cols),
// counted vmcnt(8), raw s_barrier. Writes per-row eps coefficients (a,b).
// ---------------------------------------------------------------------------
__global__ __launch_bounds__(512, 2) void vq_scan(
    const float* __restrict__ z, const char* __restrict__ bp,
    const float* __restrict__ e2,
    ull* __restrict__ partD, float* __restrict__ partD2,
    float2* __restrict__ AB)
{
    __shared__ __align__(16) char bufs[4][32768];   // 128 KB (bh of 2 cols each)
    __shared__ float e2s[2048];

    const int t    = threadIdx.x;
    const int lane = t & 63;
    const int wv   = t >> 6;
    const int hw   = blockIdx.x & 1;
    const int rg   = blockIdx.x >> 1;
    const int l31  = lane & 31;
    const int hi5  = lane >> 5;
    const int rowbase = rg * 256 + wv * 32;

    *(float4*)&e2s[t * 4] = *(const float4*)(e2 + hw * 2048 + t * 4);

    // A-hi to registers; accumulate split norms (a_l discarded)
    f16x8 a_h[16];
    float s2h = 0.0f, s2l = 0.0f;
    {
        const float* zr = z + (size_t)(rowbase + l31) * DIM + hi5 * 8;
        #pragma unroll
        for (int s = 0; s < 16; ++s) {
            float4 x0 = *(const float4*)(zr + s * 16);
            float4 x1 = *(const float4*)(zr + s * 16 + 4);
            float xs[8] = {x0.x, x0.y, x0.z, x0.w, x1.x, x1.y, x1.z, x1.w};
            #pragma unroll
            for (int j = 0; j < 8; ++j) {
                f16 h = (f16)xs[j];
                a_h[s][j] = h;
                float hv = (float)h;
                float lv = (float)((f16)((xs[j] - hv) * LOSCALE));
                s2h = fmaf(hv, hv, s2h);
                s2l = fmaf(lv, lv, s2l);
            }
        }
    }
    s2h += __shfl_xor(s2h, 32);
    s2l += __shfl_xor(s2l, 32);
    if (hw == 0 && lane < 32) {
        float nzh = sqrtf(s2h), nzl = sqrtf(s2l);
        float a = (2.0f / LOSCALE) * (nzh + nzl * INV_LOSCALE) * 1.02f;
        float b = (2.0f / LOSCALE) * nzl * 1.02f;
        AB[rowbase + lane] = make_float2(a, b);
    }

    const char* bhalf = bp + ((size_t)hw << 21);

    // stage unit u (cols 2u,2u+1; bh only; 32KB): 4 gloads/thread
#define STAGE(pb, uu) do {                                                    \
    const char* s0_ = bhalf + ((size_t)(uu) << 16)                            \
                    + (size_t)(t >> 6) * 2048 + (size_t)(t & 63) * 16;        \
    char* d0_ = bufs[pb] + t * 16;                                            \
    GLOAD16(s0_,          d0_);                                               \
    GLOAD16(s0_ + 16384,  d0_ + 8192);                                        \
    GLOAD16(s0_ + 32768,  d0_ + 16384);                                       \
    GLOAD16(s0_ + 49152,  d0_ + 24576);                                       \
    } while (0)

    STAGE(0, 0);
    STAGE(1, 1);
    __syncthreads();

    float    bestd[16], d2nd[16];
    unsigned bcol[4];
    #pragma unroll
    for (int q = 0; q < 16; ++q) { bestd[q] = 3.4e38f; d2nd[q] = 3.4e38f; }
    #pragma unroll
    for (int i = 0; i < 4; ++i) bcol[i] = 0u;

    for (int u = 0; u < 32; ++u) {
        STAGE((u + 2) & 3, u + 2);
        asm volatile("s_waitcnt vmcnt(8)" ::: "memory");
        asm volatile("s_waitcnt lgkmcnt(0)" ::: "memory");
        __builtin_amdgcn_s_barrier();
        __builtin_amdgcn_sched_barrier(0);

        const char* bu = bufs[u & 3];
        #pragma unroll
        for (int sub = 0; sub < 2; ++sub) {
            const int c = 2 * u + sub;
            const char* bb = bu + sub * 16384;
            f32x16 m0, m1;
            #pragma unroll
            for (int q = 0; q < 16; ++q) { m0[q] = 0.0f; m1[q] = 0.0f; }
            __builtin_amdgcn_s_setprio(1);
            #pragma unroll
            for (int ks = 0; ks < 16; ks += 2) {
                f16x8 b0 = *(const f16x8*)(bb + ks * 1024 + lane * 16);
                f16x8 b1 = *(const f16x8*)(bb + (ks + 1) * 1024 + lane * 16);
                m0 = __builtin_amdgcn_mfma_f32_32x32x16_f16(a_h[ks],     b0, m0, 0, 0, 0);
                m1 = __builtin_amdgcn_mfma_f32_32x32x16_f16(a_h[ks + 1], b1, m1, 0, 0, 0);
            }
            __builtin_amdgcn_s_setprio(0);

            float e2c = e2s[c * 32 + l31];
            #pragma unroll
            for (int q = 0; q < 16; ++q) {
                float d = fmaf(-2.0f, m0[q] + m1[q], e2c);
                bool lt = d < bestd[q];
                float nd2 = lt ? bestd[q] : fminf(d2nd[q], d);
                d2nd[q]  = nd2;
                bestd[q] = lt ? d : bestd[q];
                const unsigned sh = (unsigned)((q & 3) * 8);
                unsigned nv = (bcol[q >> 2] & ~(0xFFu << sh)) | ((unsigned)c << sh);
                bcol[q >> 2] = lt ? nv : bcol[q >> 2];
            }
        }
    }
#undef STAGE

    // cross-lane reduce (d1,c1,d2) over 32 code-lanes; write partials
    #pragma unroll
    for (int q = 0; q < 16; ++q) {
        float    d  = bestd[q];
        float    d2 = d2nd[q];
        unsigned c  = (unsigned)(hw * 2048) +
                      ((bcol[q >> 2] >> ((q & 3) * 8)) & 0xFFu) * 32u + (unsigned)l31;
        #pragma unroll
        for (int o2 = 16; o2; o2 >>= 1) {
            float    od  = __shfl_xor(d, o2);
            unsigned oc  = __shfl_xor(c, o2);
            float    od2 = __shfl_xor(d2, o2);
            float nd2 = fminf(fmaxf(d, od), fminf(d2, od2));
            bool sw = od < d || (od == d && oc < c);
            d = sw ? od : d;
            c = sw ? oc : c;
            d2 = nd2;
        }
        if (l31 == 0) {
            int row = (q & 3) + 8 * (q >> 2) + 4 * hi5;
            unsigned u_  = __float_as_uint(d);
            unsigned key = u_ ^ (unsigned)(((int)u_ >> 31) | 0x80000000);
            partD [(size_t)hw * 32768 + rowbase + row] = ((ull)key << 32) | c;
            partD2[(size_t)hw * 32768 + rowbase + row] = d2;
        }
    }
}

// ---------------------------------------------------------------------------
// certify rows; build uncertain list. partD[0..N) rewritten in place.
// ---------------------------------------------------------------------------
__global__ void vq_certain(ull* __restrict__ partD, const float* __restrict__ partD2,
                           const float2* __restrict__ AB,
                           const unsigned* __restrict__ melmeh,
                           int* __restrict__ list, int* __restrict__ ctr, int N)
{
    int i = blockIdx.x * blockDim.x + threadIdx.x;
    if (i >= N) return;
    ull k0 = partD[i];
    ull k1 = partD[(size_t)N + i];
    float d1a = dec_key((unsigned)(k0 >> 32));
    float d1b = dec_key((unsigned)(k1 >> 32));
    float d2a = partD2[i];
    float d2b = partD2[(size_t)N + i];
    ull  kmin = k1 < k0 ? k1 : k0;
    float gd1 = fminf(d1a, d1b);
    float gd2 = fminf(fmaxf(d1a, d1b), fminf(d2a, d2b));
    float2 ab = AB[i];
    float Mel = __uint_as_float(melmeh[0]);
    float Meh = __uint_as_float(melmeh[1]);
    float eps = fmaf(ab.x, Mel, fmaf(ab.y, Meh, EPS0));
    if (gd2 - gd1 > 2.0f * eps) {
        partD[i] = kmin;                 // certified winner
    } else {
        partD[i] = ~0ULL;                // to be filled by rescore
        int p = atomicAdd(ctr, 1);
        list[p] = i;
    }
}

// ---------------------------------------------------------------------------
// PASS 2: exact 3-term rescore of uncertain rows. 1024 slots x 4 code-chunks,
// 1 wave each; slot handles 32 listed rows, streams its 1MB chunk
// barrier-free (r4 style); atomicMin u64 keys (order-independent).
// ---------------------------------------------------------------------------
__global__ __launch_bounds__(64) void vq_rescore(
    const float* __restrict__ z, const char* __restrict__ bp,
    const float* __restrict__ e2, const int* __restrict__ list,
    const int* __restrict__ ctr, ull* __restrict__ outD)
{
    const int l    = threadIdx.x;
    const int l31  = l & 31;
    const int hi5  = l >> 5;
    const int slot  = blockIdx.x >> 2;
    const int chunk = blockIdx.x & 3;
    const int cnt = *ctr;
    if (slot * 32 >= cnt) return;

    int pos = slot * 32 + l31;
    int rid = list[pos < cnt ? pos : 0];

    f16x8 a_h[16], a_l[16];
    {
        const float* zr = z + (size_t)rid * DIM + hi5 * 8;
        #pragma unroll
        for (int s = 0; s < 16; ++s) {
            float4 x0 = *(const float4*)(zr + s * 16);
            float4 x1 = *(const float4*)(zr + s * 16 + 4);
            float xs[8] = {x0.x, x0.y, x0.z, x0.w, x1.x, x1.y, x1.z, x1.w};
            #pragma unroll
            for (int j = 0; j < 8; ++j) {
                f16 h = (f16)xs[j];
                a_h[s][j] = h;
                a_l[s][j] = (f16)((xs[j] - (float)h) * LOSCALE);
            }
        }
    }

    float    bestd[16];
    unsigned bcol[4];
    #pragma unroll
    for (int q = 0; q < 16; ++q) bestd[q] = 3.4e38f;
    #pragma unroll
    for (int i = 0; i < 4; ++i) bcol[i] = 0u;

    const char* bgp = bp + (((size_t)chunk * 32) << 15) + (size_t)l * 16;

#define LOADG(BH, BL, OFF) do {                                    \
    _Pragma("unroll")                                              \
    for (int i_ = 0; i_ < 4; ++i_) {                               \
        BH[i_] = *(const f16x8*)(bgp + (OFF) + i_ * 2048);         \
        BL[i_] = *(const f16x8*)(bgp + (OFF) + i_ * 2048 + 1024);  \
    } } while (0)

#define COMPUTE(BH, BL, G) do {                                                      \
    _Pragma("unroll")                                                                \
    for (int i_ = 0; i_ < 4; ++i_) {                                                 \
        acc0  = __builtin_amdgcn_mfma_f32_32x32x16_f16(a_h[(G)*4+i_], BH[i_], acc0,  0,0,0); \
        acc1a = __builtin_amdgcn_mfma_f32_32x32x16_f16(a_h[(G)*4+i_], BL[i_], acc1a, 0,0,0); \
        acc1b = __builtin_amdgcn_mfma_f32_32x32x16_f16(a_l[(G)*4+i_], BH[i_], acc1b, 0,0,0); \
    } } while (0)

    f16x8 h0[4], l0[4], h1[4], l1[4];
    size_t off = 0;
    LOADG(h0, l0, off); off += 8192;
    LOADG(h1, l1, off); off += 8192;

    for (int lc = 0; lc < 32; ++lc) {
        float e2c = e2[(chunk * 32 + lc) * 32 + l31];
        f32x16 acc0, acc1a, acc1b;
        #pragma unroll
        for (int q = 0; q < 16; ++q) { acc0[q] = 0.0f; acc1a[q] = 0.0f; acc1b[q] = 0.0f; }

        COMPUTE(h0, l0, 0); LOADG(h0, l0, off); off += 8192;
        COMPUTE(h1, l1, 1); LOADG(h1, l1, off); off += 8192;
        COMPUTE(h0, l0, 2); LOADG(h0, l0, off); off += 8192;
        COMPUTE(h1, l1, 3); LOADG(h1, l1, off); off += 8192;

        #pragma unroll
        for (int q = 0; q < 16; ++q) {
            float dot  = fmaf(acc1a[q] + acc1b[q], INV_LOSCALE, acc0[q]);
            float dist = fmaf(-2.0f, dot, e2c);
            bool  lt   = dist < bestd[q];
            bestd[q]   = lt ? dist : bestd[q];
            const unsigned sh = (unsigned)((q & 3) * 8);
            unsigned nv = (bcol[q >> 2] & ~(0xFFu << sh)) | ((unsigned)lc << sh);
            bcol[q >> 2] = lt ? nv : bcol[q >> 2];
        }
    }
#undef LOADG
#undef COMPUTE

    #pragma unroll
    for (int q = 0; q < 16; ++q) {
        float    d = bestd[q];
        unsigned c = ((unsigned)chunk * 32u +
                      ((bcol[q >> 2] >> ((q & 3) * 8)) & 0xFFu)) * 32u + (unsigned)l31;
        #pragma unroll
        for (int o2 = 16; o2; o2 >>= 1) {
            float    od = __shfl_xor(d, o2);
            unsigned oc = __shfl_xor(c, o2);
            if (od < d || (od == d && oc < c)) { d = od; c = oc; }
        }
        // FIX (r15 crash): shuffle with ALL lanes active, outside the guard.
        int rlocal = (q & 3) + 8 * (q >> 2) + 4 * hi5;
        int ridr   = __shfl(rid, rlocal);
        if (l31 == 0) {
            unsigned u_  = __float_as_uint(d);
            unsigned key = u_ ^ (unsigned)(((int)u_ >> 31) | 0x80000000);
            atomicMin(&outD[ridr], ((ull)key << 32) | c);
        }
    }
}

// final (1-array keys): idx extract + gather + hist
__global__ void vq_final1(const ull* __restrict__ outD, const float* __restrict__ emb,
                          float* __restrict__ idxf, float* __restrict__ zq,
                          int* __restrict__ counts, int N)
{
    int n = blockIdx.x * 4 + (threadIdx.x >> 6);
    int l = threadIdx.x & 63;
    if (n >= N) return;
    int idx = (int)(unsigned)(outD[n] & 0xffffffffu);
    idx &= 4095;   // safety: any residual bad key -> wrong answer, not a fault
    ((float4*)(zq + (size_t)n * DIM))[l] =
        ((const float4*)(emb + (size_t)idx * DIM))[l];
    if (l == 0) {
        idxf[n] = (float)idx;
        atomicAdd(&counts[idx], 1);
    }
}

// ---------------------------------------------------------------------------
// MID fallback: proven r10 full 3-term kernel + 2-half final
// ---------------------------------------------------------------------------
__global__ __launch_bounds__(512, 2) void vq_argmin10(
    const float* __restrict__ z, const char* __restrict__ bp,
    const float* __restrict__ e2, ull* __restrict__ part)
{
    __shared__ __align__(16) char bufs[4][32768];
    __shared__ float e2s[2048];
    const int t    = threadIdx.x;
    const int lane = t & 63;
    const int wv   = t >> 6;
    const int hw   = blockIdx.x & 1;
    const int rg   = blockIdx.x >> 1;
    const int l31  = lane & 31;
    const int hi5  = lane >> 5;
    const int rowbase = rg * 256 + wv * 32;

    *(float4*)&e2s[t * 4] = *(const float4*)(e2 + hw * 2048 + t * 4);

    f16x8 a_h[16], a_l[16];
    {
        const float* zr = z + (size_t)(rowbase + l31) * DIM + hi5 * 8;
        #pragma unroll
        for (int s = 0; s < 16; ++s) {
            float4 x0 = *(const float4*)(zr + s * 16);
            float4 x1 = *(const float4*)(zr + s * 16 + 4);
            float xs[8] = {x0.x, x0.y, x0.z, x0.w, x1.x, x1.y, x1.z, x1.w};
            #pragma unroll
            for (int j = 0; j < 8; ++j) {
                f16 h = (f16)xs[j];
                a_h[s][j] = h;
                a_l[s][j] = (f16)((xs[j] - (float)h) * LOSCALE);
            }
        }
    }
    const char* bhalf = bp + ((size_t)hw << 21);
#define STAGE(pb, cc) do {                                                    \
    const char* src_ = bhalf + ((size_t)(cc) << 15) + (size_t)t * 16;         \
    char* dst_ = bufs[pb] + t * 16;                                           \
    _Pragma("unroll")                                                         \
    for (int i_ = 0; i_ < 4; ++i_)                                            \
        GLOAD16(src_ + i_ * 8192, dst_ + i_ * 8192);                          \
    } while (0)
    STAGE(0, 0);
    STAGE(1, 1);
    __syncthreads();

    float    bestd[16];
    unsigned bcol[4];
    #pragma unroll
    for (int q = 0; q < 16; ++q) bestd[q] = 3.4e38f;
    #pragma unroll
    for (int i = 0; i < 4; ++i) bcol[i] = 0u;

    for (int c = 0; c < 64; ++c) {
        STAGE((c + 2) & 3, c + 2);
        asm volatile("s_waitcnt vmcnt(8)" ::: "memory");
        asm volatile("s_waitcnt lgkmcnt(0)" ::: "memory");
        __builtin_amdgcn_s_barrier();
        __builtin_amdgcn_sched_barrier(0);

        f32x16 acc0, acc1a, acc1b;
        #pragma unroll
        for (int q = 0; q < 16; ++q) { acc0[q] = 0.0f; acc1a[q] = 0.0f; acc1b[q] = 0.0f; }
        const char* bb = bufs[c & 3];
        f16x8 bh_ = *(const f16x8*)(bb + lane * 16);
        f16x8 bl_ = *(const f16x8*)(bb + 1024 + lane * 16);
        __builtin_amdgcn_s_setprio(1);
        #pragma unroll
        for (int ks = 0; ks < 16; ++ks) {
            f16x8 bhn_, bln_;
            if (ks < 15) {
                bhn_ = *(const f16x8*)(bb + (ks + 1) * 2048 + lane * 16);
                bln_ = *(const f16x8*)(bb + (ks + 1) * 2048 + 1024 + lane * 16);
            }
            acc0  = __builtin_amdgcn_mfma_f32_32x32x16_f16(a_h[ks], bh_, acc0,  0, 0, 0);
            acc1a = __builtin_amdgcn_mfma_f32_32x32x16_f16(a_h[ks], bl_, acc1a, 0, 0, 0);
            acc1b = __builtin_amdgcn_mfma_f32_32x32x16_f16(a_l[ks], bh_, acc1b, 0, 0, 0);
            if (ks < 15) { bh_ = bhn_; bl_ = bln_; }
        }
        __builtin_amdgcn_s_setprio(0);

        float e2c = e2s[c * 32 + l31];
        #pragma unroll
        for (int q = 0; q < 16; ++q) {
            float dot  = fmaf(acc1a[q] + acc1b[q], INV_LOSCALE, acc0[q]);
            float dist = fmaf(-2.0f, dot, e2c);
            bool  lt   = dist < bestd[q];
            bestd[q]   = lt ? dist : bestd[q];
            const unsigned sh = (unsigned)((q & 3) * 8);
            unsigned nv = (bcol[q >> 2] & ~(0xFFu << sh)) | ((unsigned)c << sh);
            bcol[q >> 2] = lt ? nv : bcol[q >> 2];
        }
    }
#undef STAGE
    #pragma unroll
    for (int q = 0; q < 16; ++q) {
        float    d = bestd[q];
        unsigned c = (unsigned)(hw * 2048) +
                     ((bcol[q >> 2] >> ((q & 3) * 8)) & 0xFFu) * 32u + (unsigned)l31;
        #pragma unroll
        for (int o2 = 16; o2; o2 >>= 1) {
            float    od = __shfl_xor(d, o2);
            unsigned oc = __shfl_xor(c, o2);
            if (od < d || (od == d && oc < c)) { d = od; c = oc; }
        }
        if (l31 == 0) {
            int row = (q & 3) + 8 * (q >> 2) + 4 * hi5;
            unsigned u_  = __float_as_uint(d);
            unsigned key = u_ ^ (unsigned)(((int)u_ >> 31) | 0x80000000);
            part[(size_t)hw * 32768 + rowbase + row] = ((ull)key << 32) | c;
        }
    }
}

__global__ void vq_final2h(const ull* __restrict__ part, const float* __restrict__ emb,
                           float* __restrict__ idxf, float* __restrict__ zq,
                           int* __restrict__ counts, int N)
{
    int n = blockIdx.x * 4 + (threadIdx.x >> 6);
    int l = threadIdx.x & 63;
    if (n >= N) return;
    ull a = part[n];
    ull b = part[(size_t)N + n];
    ull m = b < a ? b : a;
    int idx = (int)(unsigned)(m & 0xffffffffu) & 4095;
    ((float4*)(zq + (size_t)n * DIM))[l] =
        ((const float4*)(emb + (size_t)idx * DIM))[l];
    if (l == 0) {
        idxf[n] = (float)idx;
        atomicAdd(&counts[idx], 1);
    }
}

// ------------------------- low fallback (fp32 VALU) ------------------------
__global__ __launch_bounds__(256, 2) void vq_argmin_f32(
    const float* __restrict__ z, const float* __restrict__ emb,
    const float* __restrict__ e2, float* __restrict__ idxf, int K)
{
    __shared__ float zs[64 * 36];
    __shared__ float es[128 * 36];
    const int t = threadIdx.x;
    const int tx = t & 15;
    const int ty = t >> 4;
    const int rowbase = blockIdx.x * 64;
    const float* zbase = z + (size_t)rowbase * DIM;
    float best[4]; int bidx[4];
    #pragma unroll
    for (int i = 0; i < 4; ++i) { best[i] = 3.4e38f; bidx[i] = 0; }
    for (int kt = 0; kt < K; kt += 128) {
        float acc[4][8];
        #pragma unroll
        for (int i = 0; i < 4; ++i)
            #pragma unroll
            for (int j = 0; j < 8; ++j) acc[i][j] = 0.0f;
        for (int dc = 0; dc < DIM; dc += 32) {
            { int lr = t >> 2, o = (t & 3) * 8;
              const float* gp = zbase + (size_t)lr * DIM + dc + o;
              *(float4*)&zs[lr*36+o]   = *(const float4*)gp;
              *(float4*)&zs[lr*36+o+4] = *(const float4*)(gp+4); }
            { int lc = t >> 1, o = (t & 1) * 16;
              const float* gp = emb + (size_t)(kt+lc) * DIM + dc + o;
              *(float4*)&es[lc*36+o]    = *(const float4*)gp;
              *(float4*)&es[lc*36+o+4]  = *(const float4*)(gp+4);
              *(float4*)&es[lc*36+o+8]  = *(const float4*)(gp+8);
              *(float4*)&es[lc*36+o+12] = *(const float4*)(gp+12); }
            __syncthreads();
            const float* zp = &zs[(ty*4)*36];
            const float* ep = &es[tx*36];
            #pragma unroll
            for (int d = 0; d < 32; d += 4) {
                float4 zv[4], ev[8];
                #pragma unroll
                for (int i = 0; i < 4; ++i) zv[i] = *(const float4*)&zp[i*36+d];
                #pragma unroll
                for (int j = 0; j < 8; ++j) ev[j] = *(const float4*)&ep[j*16*36+d];
                #pragma unroll
                for (int i = 0; i < 4; ++i)
                    #pragma unroll
                    for (int j = 0; j < 8; ++j) {
                        acc[i][j] += zv[i].x*ev[j].x; acc[i][j] += zv[i].y*ev[j].y;
                        acc[i][j] += zv[i].z*ev[j].z; acc[i][j] += zv[i].w*ev[j].w;
                    }
            }
            __syncthreads();
        }
        #pragma unroll
        for (int j = 0; j < 8; ++j) {
            int c = kt + tx + 16*j;
            float ev2 = e2[c];
            #pragma unroll
            for (int i = 0; i < 4; ++i) {
                float dist = ev2 - 2.0f*acc[i][j];
                if (dist < best[i] || (dist == best[i] && c < bidx[i])) { best[i]=dist; bidx[i]=c; }
            }
        }
    }
    #pragma unroll
    for (int i = 0; i < 4; ++i) {
        float bd = best[i]; int bi = bidx[i];
        #pragma unroll
        for (int off = 8; off; off >>= 1) {
            float od = __shfl_xor(bd, off); int oi = __shfl_xor(bi, off);
            if (od < bd || (od == bd && oi < bi)) { bd = od; bi = oi; }
        }
        if (tx == 0) idxf[rowbase + ty*4 + i] = (float)bi;
    }
}

__global__ void vq_gather(const float* __restrict__ emb,
                          const float* __restrict__ idxf,
                          float* __restrict__ zq, int N)
{
    int n = blockIdx.x * 4 + (threadIdx.x >> 6);
    int l = threadIdx.x & 63;
    if (n >= N) return;
    int idx = (int)idxf[n];
    ((float4*)(zq + (size_t)n * DIM))[l] = ((const float4*)(emb + (size_t)idx * DIM))[l];
}

__global__ void vq_hist(const float* __restrict__ idxf, int* __restrict__ counts, int N) {
    int n = blockIdx.x * blockDim.x + threadIdx.x;
    if (n < N) atomicAdd(&counts[(int)idxf[n]], 1);
}

__global__ void vq_ppl(const int* __restrict__ counts, float invN,
                       float* __restrict__ out, int K)
{
    int t = threadIdx.x;
    float s = 0.0f;
    for (int k = t; k < K; k += 256) {
        float p = (float)counts[k] * invN;
        s += p * logf(p + 1e-10f);
    }
    #pragma unroll
    for (int off = 32; off; off >>= 1) s += __shfl_xor(s, off);
    __shared__ float wsum[4];
    if ((t & 63) == 0) wsum[t >> 6] = s;
    __syncthreads();
    if (t == 0) out[0] = expf(-(wsum[0] + wsum[1] + wsum[2] + wsum[3]));
}

extern "C" void kernel_launch(void* const* d_in, const int* in_sizes, int n_in,
                              void* d_out, int out_size, void* d_ws, size_t ws_size,
                              hipStream_t stream)
{
    const float* z   = (const float*)d_in[0];
    const float* emb = (const float*)d_in[1];
    const int N = in_sizes[0] / DIM;   // 32768
    const int K = in_sizes[1] / DIM;   // 4096

    float* out  = (float*)d_out;
    float* zq   = out;
    float* idxf = out + (size_t)N * DIM;
    float* ppl  = idxf + N;

    // layout
    char* base = (char*)d_ws;
    const size_t OFF_E2   = BP_BYTES;
    const size_t OFF_CNT  = OFF_E2 + 16384;
    const size_t OFF_MISC = OFF_CNT + 16384;          // ctr, mel, meh (ints)
    const size_t OFF_PART = OFF_MISC + 32;
    const size_t OFF_PD2  = OFF_PART + 524288;
    const size_t OFF_AB   = OFF_PD2 + 262144;
    const size_t OFF_LIST = OFF_AB + 262144;
    const size_t NEED_FULL = OFF_LIST + 131072;
    const size_t NEED_MID  = OFF_PART + 524288;

    if (ws_size >= NEED_FULL && K == 4096 && N == 32768) {
        f16*   bpk    = (f16*)base;
        float* e2     = (float*)(base + OFF_E2);
        int*   counts = (int*)(base + OFF_CNT);
        int*   ctr    = counts + 4096;
        unsigned* melmeh = (unsigned*)(ctr + 1);
        ull*   partD  = (ull*)(base + OFF_PART);
        float* partD2 = (float*)(base + OFF_PD2);
        float2* AB    = (float2*)(base + OFF_AB);
        int*   list   = (int*)(base + OFF_LIST);

        vq_zero<<<17, 256, 0, stream>>>(counts, 4100);       // counts+ctr+mel+meh
        vq_pack2<<<1024, 256, 0, stream>>>(emb, bpk);
        vq_e2x<<<K, 64, 0, stream>>>(emb, e2, melmeh);
        vq_scan<<<256, 512, 0, stream>>>(z, (const char*)bpk, e2, partD, partD2, AB);
        vq_certain<<<128, 256, 0, stream>>>(partD, partD2, AB, melmeh, list, ctr, N);
        vq_rescore<<<4096, 64, 0, stream>>>(z, (const char*)bpk, e2, list, ctr, partD);
        vq_final1<<<N / 4, 256, 0, stream>>>(partD, emb, idxf, zq, counts, N);
        vq_ppl<<<1, 256, 0, stream>>>(counts, 1.0f / (float)N, ppl, K);
    } else if (ws_size >= NEED_MID && K == 4096 && N == 32768) {
        f16*   bpk    = (f16*)base;
        float* e2     = (float*)(base + OFF_E2);
        int*   counts = (int*)(base + OFF_CNT);
        ull*   part   = (ull*)(base + OFF_PART);

        vq_zero<<<16, 256, 0, stream>>>(counts, 4096);
        vq_pack2<<<1024, 256, 0, stream>>>(emb, bpk);
        vq_e2<<<K, 64, 0, stream>>>(emb, e2);
        vq_argmin10<<<(N / 256) * 2, 512, 0, stream>>>(z, (const char*)bpk, e2, part);
        vq_final2h<<<N / 4, 256, 0, stream>>>(part, emb, idxf, zq, counts, N);
        vq_ppl<<<1, 256, 0, stream>>>(counts, 1.0f / (float)N, ppl, K);
    } else {
        float* e2     = (float*)d_ws;
        int*   counts = (int*)((char*)d_ws + (size_t)K * sizeof(float));
        vq_e2<<<K, 64, 0, stream>>>(emb, e2);
        vq_zero<<<(K + 255) / 256, 256, 0, stream>>>(counts, K);
        vq_argmin_f32<<<N / 64, 256, 0, stream>>>(z, emb, e2, idxf, K);
        vq_gather<<<N / 4, 256, 0, stream>>>(emb, idxf, zq, N);
        vq_hist<<<(N + 255) / 256, 256, 0, stream>>>(idxf, counts, N);
        vq_ppl<<<1, 256, 0, stream>>>(counts, 1.0f / (float)N, ppl, K);
    }
}

// Round 17
// 284.158 us; speedup vs baseline: 1.1128x; 1.1128x over previous
//
#include <hip/hip_runtime.h>
#include <hip/hip_bf16.h>
#include <math.h>
#include <stdint.h>

typedef _Float16 f16;
typedef _Float16 f16x8 __attribute__((ext_vector_type(8)));
typedef float f32x16 __attribute__((ext_vector_type(16)));
typedef unsigned long long ull;

#define DIM 256
#define LOSCALE 2048.0f
#define INV_LOSCALE (1.0f/2048.0f)
#define EPS0 0.02f

// B' stream: 4096 codes x 256 depth x {hi,lo}, fragment-major:
// byte offset = col*32768 + s*2048 + t*1024 + lane*16
// (col 0..127 = 32 codes each, k-step s 0..15, t 0:hi 1:lo)
// lane l holds 16B = e[code=col*32+(l&31)][depth=s*16+(l>>5)*8 .. +8]
#define BP_BYTES (4096u*1024u + 98304u)   // 4MB + pad (staging/prefetch overrun)

#define GLOAD16(gp, lp) __builtin_amdgcn_global_load_lds( \
    (const __attribute__((address_space(1))) void*)(gp),  \
    (__attribute__((address_space(3))) void*)(lp), 16, 0, 0)

// monotonic key decode (enc: u ^ ((int(u)>>31)|0x80000000))
__device__ __forceinline__ float dec_key(unsigned k) {
    unsigned u = (k & 0x80000000u) ? (k ^ 0x80000000u) : ~k;
    return __uint_as_float(u);
}

// ---------------------------------------------------------------------------
// pack codebook into fragment-major hi/lo f16 stream
// ---------------------------------------------------------------------------
__global__ void vq_pack2(const float* __restrict__ emb, f16* __restrict__ bp)
{
    int o = blockIdx.x * blockDim.x + threadIdx.x;
    int l = o & 63;
    int b = o >> 6;
    int t   = b & 1;
    int s   = (b >> 1) & 15;
    int col = b >> 5;
    int code  = col * 32 + (l & 31);
    int depth = s * 16 + (l >> 5) * 8;
    const float* gp = emb + (size_t)code * DIM + depth;
    float4 x0 = *(const float4*)gp;
    float4 x1 = *(const float4*)(gp + 4);
    float xs[8] = {x0.x, x0.y, x0.z, x0.w, x1.x, x1.y, x1.z, x1.w};
    f16x8 v;
    #pragma unroll
    for (int j = 0; j < 8; ++j) {
        f16 h = (f16)xs[j];
        v[j] = t ? (f16)((xs[j] - (float)h) * LOSCALE) : h;
    }
    *(f16x8*)(bp + (size_t)o * 8) = v;
}

// ||e||^2 exact + global split-norm maxima (Mel, Meh) via atomicMax
__global__ void vq_e2x(const float* __restrict__ emb, float* __restrict__ e2,
                       unsigned* __restrict__ melmeh)
{
    int k = blockIdx.x;
    int l = threadIdx.x;
    float4 v = ((const float4*)(emb + (size_t)k * DIM))[l];
    float xs[4] = {v.x, v.y, v.z, v.w};
    float s = 0.0f, sh = 0.0f, sl = 0.0f;
    #pragma unroll
    for (int j = 0; j < 4; ++j) {
        float x = xs[j];
        s = fmaf(x, x, s);
        f16 h = (f16)x;
        float hv = (float)h;
        float lv = (float)((f16)((x - hv) * LOSCALE));
        sh = fmaf(hv, hv, sh);
        sl = fmaf(lv, lv, sl);
    }
    #pragma unroll
    for (int off = 32; off; off >>= 1) {
        s  += __shfl_xor(s, off);
        sh += __shfl_xor(sh, off);
        sl += __shfl_xor(sl, off);
    }
    if (l == 0) {
        e2[k] = s;
        atomicMax(&melmeh[0], __float_as_uint(sqrtf(sl)));   // Mel
        atomicMax(&melmeh[1], __float_as_uint(sqrtf(sh)));   // Meh
    }
}

// plain e2 (low fallback path)
__global__ void vq_e2(const float* __restrict__ emb, float* __restrict__ e2) {
    int k = blockIdx.x;
    int l = threadIdx.x;
    float4 v = ((const float4*)(emb + (size_t)k * DIM))[l];
    float s = v.x*v.x + v.y*v.y + v.z*v.z + v.w*v.w;
    #pragma unroll
    for (int off = 32; off; off >>= 1) s += __shfl_xor(s, off);
    if (l == 0) e2[k] = s;
}

__global__ void vq_zero(int* __restrict__ p, int n) {
    int i = blockIdx.x * blockDim.x + threadIdx.x;
    if (i < n) p[i] = 0;
}

// ---------------------------------------------------------------------------
// PASS 1: hi-only scan with (d1,c1,d2) tracking. r10 skeleton:
// 512 thr = 8 waves x 32 rows, one code half; 4 x 32KB units (bh of 2 cols),
// counted vmcnt(8), raw s_barrier. Writes per-row eps coefficients (a,b).
// ---------------------------------------------------------------------------
__global__ __launch_bounds__(512, 2) void vq_scan(
    const float* __restrict__ z, const char* __restrict__ bp,
    const float* __restrict__ e2,
    ull* __restrict__ partD, float* __restrict__ partD2,
    float2* __restrict__ AB)
{
    __shared__ __align__(16) char bufs[4][32768];   // 128 KB (bh of 2 cols each)
    __shared__ float e2s[2048];

    const int t    = threadIdx.x;
    const int lane = t & 63;
    const int wv   = t >> 6;
    const int hw   = blockIdx.x & 1;
    const int rg   = blockIdx.x >> 1;
    const int l31  = lane & 31;
    const int hi5  = lane >> 5;
    const int rowbase = rg * 256 + wv * 32;

    *(float4*)&e2s[t * 4] = *(const float4*)(e2 + hw * 2048 + t * 4);

    // A-hi to registers; accumulate split norms (a_l discarded)
    f16x8 a_h[16];
    float s2h = 0.0f, s2l = 0.0f;
    {
        const float* zr = z + (size_t)(rowbase + l31) * DIM + hi5 * 8;
        #pragma unroll
        for (int s = 0; s < 16; ++s) {
            float4 x0 = *(const float4*)(zr + s * 16);
            float4 x1 = *(const float4*)(zr + s * 16 + 4);
            float xs[8] = {x0.x, x0.y, x0.z, x0.w, x1.x, x1.y, x1.z, x1.w};
            #pragma unroll
            for (int j = 0; j < 8; ++j) {
                f16 h = (f16)xs[j];
                a_h[s][j] = h;
                float hv = (float)h;
                float lv = (float)((f16)((xs[j] - hv) * LOSCALE));
                s2h = fmaf(hv, hv, s2h);
                s2l = fmaf(lv, lv, s2l);
            }
        }
    }
    s2h += __shfl_xor(s2h, 32);
    s2l += __shfl_xor(s2l, 32);
    if (hw == 0 && lane < 32) {
        float nzh = sqrtf(s2h), nzl = sqrtf(s2l);
        float a = (2.0f / LOSCALE) * (nzh + nzl * INV_LOSCALE) * 1.02f;
        float b = (2.0f / LOSCALE) * nzl * 1.02f;
        AB[rowbase + lane] = make_float2(a, b);
    }

    const char* bhalf = bp + ((size_t)hw << 21);

    // stage unit u (cols 2u,2u+1; bh only; 32KB): 4 gloads/thread
#define STAGE(pb, uu) do {                                                    \
    const char* s0_ = bhalf + ((size_t)(uu) << 16)                            \
                    + (size_t)(t >> 6) * 2048 + (size_t)(t & 63) * 16;        \
    char* d0_ = bufs[pb] + t * 16;                                            \
    GLOAD16(s0_,          d0_);                                               \
    GLOAD16(s0_ + 16384,  d0_ + 8192);                                        \
    GLOAD16(s0_ + 32768,  d0_ + 16384);                                       \
    GLOAD16(s0_ + 49152,  d0_ + 24576);                                       \
    } while (0)

    STAGE(0, 0);
    STAGE(1, 1);
    __syncthreads();

    float    bestd[16], d2nd[16];
    unsigned bcol[4];
    #pragma unroll
    for (int q = 0; q < 16; ++q) { bestd[q] = 3.4e38f; d2nd[q] = 3.4e38f; }
    #pragma unroll
    for (int i = 0; i < 4; ++i) bcol[i] = 0u;

    for (int u = 0; u < 32; ++u) {
        STAGE((u + 2) & 3, u + 2);
        asm volatile("s_waitcnt vmcnt(8)" ::: "memory");
        asm volatile("s_waitcnt lgkmcnt(0)" ::: "memory");
        __builtin_amdgcn_s_barrier();
        __builtin_amdgcn_sched_barrier(0);

        const char* bu = bufs[u & 3];
        #pragma unroll
        for (int sub = 0; sub < 2; ++sub) {
            const int c = 2 * u + sub;
            const char* bb = bu + sub * 16384;
            f32x16 m0, m1;
            #pragma unroll
            for (int q = 0; q < 16; ++q) { m0[q] = 0.0f; m1[q] = 0.0f; }
            __builtin_amdgcn_s_setprio(1);
            #pragma unroll
            for (int ks = 0; ks < 16; ks += 2) {
                f16x8 b0 = *(const f16x8*)(bb + ks * 1024 + lane * 16);
                f16x8 b1 = *(const f16x8*)(bb + (ks + 1) * 1024 + lane * 16);
                m0 = __builtin_amdgcn_mfma_f32_32x32x16_f16(a_h[ks],     b0, m0, 0, 0, 0);
                m1 = __builtin_amdgcn_mfma_f32_32x32x16_f16(a_h[ks + 1], b1, m1, 0, 0, 0);
            }
            __builtin_amdgcn_s_setprio(0);

            float e2c = e2s[c * 32 + l31];
            #pragma unroll
            for (int q = 0; q < 16; ++q) {
                float d = fmaf(-2.0f, m0[q] + m1[q], e2c);
                bool lt = d < bestd[q];
                float nd2 = lt ? bestd[q] : fminf(d2nd[q], d);
                d2nd[q]  = nd2;
                bestd[q] = lt ? d : bestd[q];
                const unsigned sh = (unsigned)((q & 3) * 8);
                unsigned nv = (bcol[q >> 2] & ~(0xFFu << sh)) | ((unsigned)c << sh);
                bcol[q >> 2] = lt ? nv : bcol[q >> 2];
            }
        }
    }
#undef STAGE

    // cross-lane reduce (d1,c1,d2) over 32 code-lanes; write partials
    #pragma unroll
    for (int q = 0; q < 16; ++q) {
        float    d  = bestd[q];
        float    d2 = d2nd[q];
        unsigned c  = (unsigned)(hw * 2048) +
                      ((bcol[q >> 2] >> ((q & 3) * 8)) & 0xFFu) * 32u + (unsigned)l31;
        #pragma unroll
        for (int o2 = 16; o2; o2 >>= 1) {
            float    od  = __shfl_xor(d, o2);
            unsigned oc  = __shfl_xor(c, o2);
            float    od2 = __shfl_xor(d2, o2);
            float nd2 = fminf(fmaxf(d, od), fminf(d2, od2));
            bool sw = od < d || (od == d && oc < c);
            d = sw ? od : d;
            c = sw ? oc : c;
            d2 = nd2;
        }
        if (l31 == 0) {
            int row = (q & 3) + 8 * (q >> 2) + 4 * hi5;
            unsigned u_  = __float_as_uint(d);
            unsigned key = u_ ^ (unsigned)(((int)u_ >> 31) | 0x80000000);
            partD [(size_t)hw * 32768 + rowbase + row] = ((ull)key << 32) | c;
            partD2[(size_t)hw * 32768 + rowbase + row] = d2;
        }
    }
}

// ---------------------------------------------------------------------------
// certify rows; build uncertain list. partD[0..N) rewritten in place.
// ---------------------------------------------------------------------------
__global__ void vq_certain(ull* __restrict__ partD, const float* __restrict__ partD2,
                           const float2* __restrict__ AB,
                           const unsigned* __restrict__ melmeh,
                           int* __restrict__ list, int* __restrict__ ctr, int N)
{
    int i = blockIdx.x * blockDim.x + threadIdx.x;
    if (i >= N) return;
    ull k0 = partD[i];
    ull k1 = partD[(size_t)N + i];
    float d1a = dec_key((unsigned)(k0 >> 32));
    float d1b = dec_key((unsigned)(k1 >> 32));
    float d2a = partD2[i];
    float d2b = partD2[(size_t)N + i];
    ull  kmin = k1 < k0 ? k1 : k0;
    float gd1 = fminf(d1a, d1b);
    float gd2 = fminf(fmaxf(d1a, d1b), fminf(d2a, d2b));
    float2 ab = AB[i];
    float Mel = __uint_as_float(melmeh[0]);
    float Meh = __uint_as_float(melmeh[1]);
    float eps = fmaf(ab.x, Mel, fmaf(ab.y, Meh, EPS0));
    if (gd2 - gd1 > 2.0f * eps) {
        partD[i] = kmin;                 // certified winner
    } else {
        partD[i] = ~0ULL;                // to be filled by rescore
        int p = atomicAdd(ctr, 1);
        list[p] = i;
    }
}

// ---------------------------------------------------------------------------
// PASS 2 (dense): exact 3-term rescore of uncertain rows with the r10 block
// structure. Fixed grid 256 = 8 rgslots x 32 code-chunks (128 codes each).
// Each block grid-strides rgslots over the compacted list; 8 waves x 32
// gathered rows; 4 staged cols; atomicMin u64 keys (order-independent).
// ---------------------------------------------------------------------------
__global__ __launch_bounds__(512, 2) void vq_rescore2(
    const float* __restrict__ z, const char* __restrict__ bp,
    const float* __restrict__ e2, const int* __restrict__ list,
    const int* __restrict__ ctr, ull* __restrict__ outD)
{
    __shared__ __align__(16) char bufs[2][32768];

    const int t    = threadIdx.x;
    const int lane = t & 63;
    const int wv   = t >> 6;
    const int l31  = lane & 31;
    const int hi5  = lane >> 5;
    const int rgslot = blockIdx.x >> 5;   // 0..7
    const int chunk  = blockIdx.x & 31;   // 0..31
    const int cnt  = *ctr;

#define STAGE(pb, cc) do {                                                    \
    const char* src_ = bp + ((size_t)(cc) << 15) + (size_t)t * 16;            \
    char* dst_ = bufs[pb] + t * 16;                                           \
    _Pragma("unroll")                                                         \
    for (int i_ = 0; i_ < 4; ++i_)                                            \
        GLOAD16(src_ + i_ * 8192, dst_ + i_ * 8192);                          \
    } while (0)

    for (int rg = rgslot; rg * 256 < cnt; rg += 8) {
        int pos = rg * 256 + wv * 32 + l31;
        int rid = list[pos < cnt ? pos : 0];

        // A panel (gathered row) to registers, hi/lo split
        f16x8 a_h[16], a_l[16];
        {
            const float* zr = z + (size_t)rid * DIM + hi5 * 8;
            #pragma unroll
            for (int s = 0; s < 16; ++s) {
                float4 x0 = *(const float4*)(zr + s * 16);
                float4 x1 = *(const float4*)(zr + s * 16 + 4);
                float xs[8] = {x0.x, x0.y, x0.z, x0.w, x1.x, x1.y, x1.z, x1.w};
                #pragma unroll
                for (int j = 0; j < 8; ++j) {
                    f16 h = (f16)xs[j];
                    a_h[s][j] = h;
                    a_l[s][j] = (f16)((xs[j] - (float)h) * LOSCALE);
                }
            }
        }

        float    bestd[16];
        unsigned bcol[4];
        #pragma unroll
        for (int q = 0; q < 16; ++q) bestd[q] = 3.4e38f;
        #pragma unroll
        for (int i = 0; i < 4; ++i) bcol[i] = 0u;

        STAGE(0, chunk * 4);
        __syncthreads();

        #pragma unroll
        for (int cc = 0; cc < 4; ++cc) {
            if (cc < 3) STAGE((cc + 1) & 1, chunk * 4 + cc + 1);

            f32x16 acc0, acc1a, acc1b;
            #pragma unroll
            for (int q = 0; q < 16; ++q) { acc0[q] = 0.0f; acc1a[q] = 0.0f; acc1b[q] = 0.0f; }
            const char* bb = bufs[cc & 1];
            f16x8 bh_ = *(const f16x8*)(bb + lane * 16);
            f16x8 bl_ = *(const f16x8*)(bb + 1024 + lane * 16);
            __builtin_amdgcn_s_setprio(1);
            #pragma unroll
            for (int ks = 0; ks < 16; ++ks) {
                f16x8 bhn_, bln_;
                if (ks < 15) {
                    bhn_ = *(const f16x8*)(bb + (ks + 1) * 2048 + lane * 16);
                    bln_ = *(const f16x8*)(bb + (ks + 1) * 2048 + 1024 + lane * 16);
                }
                acc0  = __builtin_amdgcn_mfma_f32_32x32x16_f16(a_h[ks], bh_, acc0,  0, 0, 0);
                acc1a = __builtin_amdgcn_mfma_f32_32x32x16_f16(a_h[ks], bl_, acc1a, 0, 0, 0);
                acc1b = __builtin_amdgcn_mfma_f32_32x32x16_f16(a_l[ks], bh_, acc1b, 0, 0, 0);
                if (ks < 15) { bh_ = bhn_; bl_ = bln_; }
            }
            __builtin_amdgcn_s_setprio(0);

            float e2c = e2[(chunk * 4 + cc) * 32 + l31];
            #pragma unroll
            for (int q = 0; q < 16; ++q) {
                float dot  = fmaf(acc1a[q] + acc1b[q], INV_LOSCALE, acc0[q]);
                float dist = fmaf(-2.0f, dot, e2c);
                bool  lt   = dist < bestd[q];
                bestd[q]   = lt ? dist : bestd[q];
                const unsigned sh = (unsigned)((q & 3) * 8);
                unsigned nv = (bcol[q >> 2] & ~(0xFFu << sh)) | ((unsigned)cc << sh);
                bcol[q >> 2] = lt ? nv : bcol[q >> 2];
            }
            __syncthreads();   // staged col visible; buf free for overwrite
        }

        // reduce across 32 code-lanes; atomicMin partial keys
        #pragma unroll
        for (int q = 0; q < 16; ++q) {
            float    d = bestd[q];
            unsigned c = (unsigned)chunk * 128u +
                         ((bcol[q >> 2] >> ((q & 3) * 8)) & 0xFFu) * 32u + (unsigned)l31;
            #pragma unroll
            for (int o2 = 16; o2; o2 >>= 1) {
                float    od = __shfl_xor(d, o2);
                unsigned oc = __shfl_xor(c, o2);
                if (od < d || (od == d && oc < c)) { d = od; c = oc; }
            }
            // shuffle with ALL lanes active, outside the guard
            int rlocal = (q & 3) + 8 * (q >> 2) + 4 * hi5;
            int ridr   = __shfl(rid, rlocal);
            if (l31 == 0) {
                unsigned u_  = __float_as_uint(d);
                unsigned key = u_ ^ (unsigned)(((int)u_ >> 31) | 0x80000000);
                atomicMin(&outD[ridr], ((ull)key << 32) | c);
            }
        }
        __syncthreads();   // all reads of bufs done before next rg restages
    }
#undef STAGE
}

// final (1-array keys): idx extract + gather + hist
__global__ void vq_final1(const ull* __restrict__ outD, const float* __restrict__ emb,
                          float* __restrict__ idxf, float* __restrict__ zq,
                          int* __restrict__ counts, int N)
{
    int n = blockIdx.x * 4 + (threadIdx.x >> 6);
    int l = threadIdx.x & 63;
    if (n >= N) return;
    int idx = (int)(unsigned)(outD[n] & 0xffffffffu);
    idx &= 4095;   // safety: any residual bad key -> wrong answer, not a fault
    ((float4*)(zq + (size_t)n * DIM))[l] =
        ((const float4*)(emb + (size_t)idx * DIM))[l];
    if (l == 0) {
        idxf[n] = (float)idx;
        atomicAdd(&counts[idx], 1);
    }
}

// ---------------------------------------------------------------------------
// MID fallback: proven r10 full 3-term kernel + 2-half final
// ---------------------------------------------------------------------------
__global__ __launch_bounds__(512, 2) void vq_argmin10(
    const float* __restrict__ z, const char* __restrict__ bp,
    const float* __restrict__ e2, ull* __restrict__ part)
{
    __shared__ __align__(16) char bufs[4][32768];
    __shared__ float e2s[2048];
    const int t    = threadIdx.x;
    const int lane = t & 63;
    const int wv   = t >> 6;
    const int hw   = blockIdx.x & 1;
    const int rg   = blockIdx.x >> 1;
    const int l31  = lane & 31;
    const int hi5  = lane >> 5;
    const int rowbase = rg * 256 + wv * 32;

    *(float4*)&e2s[t * 4] = *(const float4*)(e2 + hw * 2048 + t * 4);

    f16x8 a_h[16], a_l[16];
    {
        const float* zr = z + (size_t)(rowbase + l31) * DIM + hi5 * 8;
        #pragma unroll
        for (int s = 0; s < 16; ++s) {
            float4 x0 = *(const float4*)(zr + s * 16);
            float4 x1 = *(const float4*)(zr + s * 16 + 4);
            float xs[8] = {x0.x, x0.y, x0.z, x0.w, x1.x, x1.y, x1.z, x1.w};
            #pragma unroll
            for (int j = 0; j < 8; ++j) {
                f16 h = (f16)xs[j];
                a_h[s][j] = h;
                a_l[s][j] = (f16)((xs[j] - (float)h) * LOSCALE);
            }
        }
    }
    const char* bhalf = bp + ((size_t)hw << 21);
#define STAGE(pb, cc) do {                                                    \
    const char* src_ = bhalf + ((size_t)(cc) << 15) + (size_t)t * 16;         \
    char* dst_ = bufs[pb] + t * 16;                                           \
    _Pragma("unroll")                                                         \
    for (int i_ = 0; i_ < 4; ++i_)                                            \
        GLOAD16(src_ + i_ * 8192, dst_ + i_ * 8192);                          \
    } while (0)
    STAGE(0, 0);
    STAGE(1, 1);
    __syncthreads();

    float    bestd[16];
    unsigned bcol[4];
    #pragma unroll
    for (int q = 0; q < 16; ++q) bestd[q] = 3.4e38f;
    #pragma unroll
    for (int i = 0; i < 4; ++i) bcol[i] = 0u;

    for (int c = 0; c < 64; ++c) {
        STAGE((c + 2) & 3, c + 2);
        asm volatile("s_waitcnt vmcnt(8)" ::: "memory");
        asm volatile("s_waitcnt lgkmcnt(0)" ::: "memory");
        __builtin_amdgcn_s_barrier();
        __builtin_amdgcn_sched_barrier(0);

        f32x16 acc0, acc1a, acc1b;
        #pragma unroll
        for (int q = 0; q < 16; ++q) { acc0[q] = 0.0f; acc1a[q] = 0.0f; acc1b[q] = 0.0f; }
        const char* bb = bufs[c & 3];
        f16x8 bh_ = *(const f16x8*)(bb + lane * 16);
        f16x8 bl_ = *(const f16x8*)(bb + 1024 + lane * 16);
        __builtin_amdgcn_s_setprio(1);
        #pragma unroll
        for (int ks = 0; ks < 16; ++ks) {
            f16x8 bhn_, bln_;
            if (ks < 15) {
                bhn_ = *(const f16x8*)(bb + (ks + 1) * 2048 + lane * 16);
                bln_ = *(const f16x8*)(bb + (ks + 1) * 2048 + 1024 + lane * 16);
            }
            acc0  = __builtin_amdgcn_mfma_f32_32x32x16_f16(a_h[ks], bh_, acc0,  0, 0, 0);
            acc1a = __builtin_amdgcn_mfma_f32_32x32x16_f16(a_h[ks], bl_, acc1a, 0, 0, 0);
            acc1b = __builtin_amdgcn_mfma_f32_32x32x16_f16(a_l[ks], bh_, acc1b, 0, 0, 0);
            if (ks < 15) { bh_ = bhn_; bl_ = bln_; }
        }
        __builtin_amdgcn_s_setprio(0);

        float e2c = e2s[c * 32 + l31];
        #pragma unroll
        for (int q = 0; q < 16; ++q) {
            float dot  = fmaf(acc1a[q] + acc1b[q], INV_LOSCALE, acc0[q]);
            float dist = fmaf(-2.0f, dot, e2c);
            bool  lt   = dist < bestd[q];
            bestd[q]   = lt ? dist : bestd[q];
            const unsigned sh = (unsigned)((q & 3) * 8);
            unsigned nv = (bcol[q >> 2] & ~(0xFFu << sh)) | ((unsigned)c << sh);
            bcol[q >> 2] = lt ? nv : bcol[q >> 2];
        }
    }
#undef STAGE
    #pragma unroll
    for (int q = 0; q < 16; ++q) {
        float    d = bestd[q];
        unsigned c = (unsigned)(hw * 2048) +
                     ((bcol[q >> 2] >> ((q & 3) * 8)) & 0xFFu) * 32u + (unsigned)l31;
        #pragma unroll
        for (int o2 = 16; o2; o2 >>= 1) {
            float    od = __shfl_xor(d, o2);
            unsigned oc = __shfl_xor(c, o2);
            if (od < d || (od == d && oc < c)) { d = od; c = oc; }
        }
        if (l31 == 0) {
            int row = (q & 3) + 8 * (q >> 2) + 4 * hi5;
            unsigned u_  = __float_as_uint(d);
            unsigned key = u_ ^ (unsigned)(((int)u_ >> 31) | 0x80000000);
            part[(size_t)hw * 32768 + rowbase + row] = ((ull)key << 32) | c;
        }
    }
}

__global__ void vq_final2h(const ull* __restrict__ part, const float* __restrict__ emb,
                           float* __restrict__ idxf, float* __restrict__ zq,
                           int* __restrict__ counts, int N)
{
    int n = blockIdx.x * 4 + (threadIdx.x >> 6);
    int l = threadIdx.x & 63;
    if (n >= N) return;
    ull a = part[n];
    ull b = part[(size_t)N + n];
    ull m = b < a ? b : a;
    int idx = (int)(unsigned)(m & 0xffffffffu) & 4095;
    ((float4*)(zq + (size_t)n * DIM))[l] =
        ((const float4*)(emb + (size_t)idx * DIM))[l];
    if (l == 0) {
        idxf[n] = (float)idx;
        atomicAdd(&counts[idx], 1);
    }
}

// ------------------------- low fallback (fp32 VALU) ------------------------
__global__ __launch_bounds__(256, 2) void vq_argmin_f32(
    const float* __restrict__ z, const float* __restrict__ emb,
    const float* __restrict__ e2, float* __restrict__ idxf, int K)
{
    __shared__ float zs[64 * 36];
    __shared__ float es[128 * 36];
    const int t = threadIdx.x;
    const int tx = t & 15;
    const int ty = t >> 4;
    const int rowbase = blockIdx.x * 64;
    const float* zbase = z + (size_t)rowbase * DIM;
    float best[4]; int bidx[4];
    #pragma unroll
    for (int i = 0; i < 4; ++i) { best[i] = 3.4e38f; bidx[i] = 0; }
    for (int kt = 0; kt < K; kt += 128) {
        float acc[4][8];
        #pragma unroll
        for (int i = 0; i < 4; ++i)
            #pragma unroll
            for (int j = 0; j < 8; ++j) acc[i][j] = 0.0f;
        for (int dc = 0; dc < DIM; dc += 32) {
            { int lr = t >> 2, o = (t & 3) * 8;
              const float* gp = zbase + (size_t)lr * DIM + dc + o;
              *(float4*)&zs[lr*36+o]   = *(const float4*)gp;
              *(float4*)&zs[lr*36+o+4] = *(const float4*)(gp+4); }
            { int lc = t >> 1, o = (t & 1) * 16;
              const float* gp = emb + (size_t)(kt+lc) * DIM + dc + o;
              *(float4*)&es[lc*36+o]    = *(const float4*)gp;
              *(float4*)&es[lc*36+o+4]  = *(const float4*)(gp+4);
              *(float4*)&es[lc*36+o+8]  = *(const float4*)(gp+8);
              *(float4*)&es[lc*36+o+12] = *(const float4*)(gp+12); }
            __syncthreads();
            const float* zp = &zs[(ty*4)*36];
            const float* ep = &es[tx*36];
            #pragma unroll
            for (int d = 0; d < 32; d += 4) {
                float4 zv[4], ev[8];
                #pragma unroll
                for (int i = 0; i < 4; ++i) zv[i] = *(const float4*)&zp[i*36+d];
                #pragma unroll
                for (int j = 0; j < 8; ++j) ev[j] = *(const float4*)&ep[j*16*36+d];
                #pragma unroll
                for (int i = 0; i < 4; ++i)
                    #pragma unroll
                    for (int j = 0; j < 8; ++j) {
                        acc[i][j] += zv[i].x*ev[j].x; acc[i][j] += zv[i].y*ev[j].y;
                        acc[i][j] += zv[i].z*ev[j].z; acc[i][j] += zv[i].w*ev[j].w;
                    }
            }
            __syncthreads();
        }
        #pragma unroll
        for (int j = 0; j < 8; ++j) {
            int c = kt + tx + 16*j;
            float ev2 = e2[c];
            #pragma unroll
            for (int i = 0; i < 4; ++i) {
                float dist = ev2 - 2.0f*acc[i][j];
                if (dist < best[i] || (dist == best[i] && c < bidx[i])) { best[i]=dist; bidx[i]=c; }
            }
        }
    }
    #pragma unroll
    for (int i = 0; i < 4; ++i) {
        float bd = best[i]; int bi = bidx[i];
        #pragma unroll
        for (int off = 8; off; off >>= 1) {
            float od = __shfl_xor(bd, off); int oi = __shfl_xor(bi, off);
            if (od < bd || (od == bd && oi < bi)) { bd = od; bi = oi; }
        }
        if (tx == 0) idxf[rowbase + ty*4 + i] = (float)bi;
    }
}

__global__ void vq_gather(const float* __restrict__ emb,
                          const float* __restrict__ idxf,
                          float* __restrict__ zq, int N)
{
    int n = blockIdx.x * 4 + (threadIdx.x >> 6);
    int l = threadIdx.x & 63;
    if (n >= N) return;
    int idx = (int)idxf[n];
    ((float4*)(zq + (size_t)n * DIM))[l] = ((const float4*)(emb + (size_t)idx * DIM))[l];
}

__global__ void vq_hist(const float* __restrict__ idxf, int* __restrict__ counts, int N) {
    int n = blockIdx.x * blockDim.x + threadIdx.x;
    if (n < N) atomicAdd(&counts[(int)idxf[n]], 1);
}

__global__ void vq_ppl(const int* __restrict__ counts, float invN,
                       float* __restrict__ out, int K)
{
    int t = threadIdx.x;
    float s = 0.0f;
    for (int k = t; k < K; k += 256) {
        float p = (float)counts[k] * invN;
        s += p * logf(p + 1e-10f);
    }
    #pragma unroll
    for (int off = 32; off; off >>= 1) s += __shfl_xor(s, off);
    __shared__ float wsum[4];
    if ((t & 63) == 0) wsum[t >> 6] = s;
    __syncthreads();
    if (t == 0) out[0] = expf(-(wsum[0] + wsum[1] + wsum[2] + wsum[3]));
}

extern "C" void kernel_launch(void* const* d_in, const int* in_sizes, int n_in,
                              void* d_out, int out_size, void* d_ws, size_t ws_size,
                              hipStream_t stream)
{
    const float* z   = (const float*)d_in[0];
    const float* emb = (const float*)d_in[1];
    const int N = in_sizes[0] / DIM;   // 32768
    const int K = in_sizes[1] / DIM;   // 4096

    float* out  = (float*)d_out;
    float* zq   = out;
    float* idxf = out + (size_t)N * DIM;
    float* ppl  = idxf + N;

    // layout
    char* base = (char*)d_ws;
    const size_t OFF_E2   = BP_BYTES;
    const size_t OFF_CNT  = OFF_E2 + 16384;
    const size_t OFF_MISC = OFF_CNT + 16384;          // ctr, mel, meh (ints)
    const size_t OFF_PART = OFF_MISC + 32;
    const size_t OFF_PD2  = OFF_PART + 524288;
    const size_t OFF_AB   = OFF_PD2 + 262144;
    const size_t OFF_LIST = OFF_AB + 262144;
    const size_t NEED_FULL = OFF_LIST + 131072;
    const size_t NEED_MID  = OFF_PART + 524288;

    if (ws_size >= NEED_FULL && K == 4096 && N == 32768) {
        f16*   bpk    = (f16*)base;
        float* e2     = (float*)(base + OFF_E2);
        int*   counts = (int*)(base + OFF_CNT);
        int*   ctr    = counts + 4096;
        unsigned* melmeh = (unsigned*)(ctr + 1);
        ull*   partD  = (ull*)(base + OFF_PART);
        float* partD2 = (float*)(base + OFF_PD2);
        float2* AB    = (float2*)(base + OFF_AB);
        int*   list   = (int*)(base + OFF_LIST);

        vq_zero<<<17, 256, 0, stream>>>(counts, 4100);       // counts+ctr+mel+meh
        vq_pack2<<<1024, 256, 0, stream>>>(emb, bpk);
        vq_e2x<<<K, 64, 0, stream>>>(emb, e2, melmeh);
        vq_scan<<<256, 512, 0, stream>>>(z, (const char*)bpk, e2, partD, partD2, AB);
        vq_certain<<<128, 256, 0, stream>>>(partD, partD2, AB, melmeh, list, ctr, N);
        vq_rescore2<<<256, 512, 0, stream>>>(z, (const char*)bpk, e2, list, ctr, partD);
        vq_final1<<<N / 4, 256, 0, stream>>>(partD, emb, idxf, zq, counts, N);
        vq_ppl<<<1, 256, 0, stream>>>(counts, 1.0f / (float)N, ppl, K);
    } else if (ws_size >= NEED_MID && K == 4096 && N == 32768) {
        f16*   bpk    = (f16*)base;
        float* e2     = (float*)(base + OFF_E2);
        int*   counts = (int*)(base + OFF_CNT);
        ull*   part   = (ull*)(base + OFF_PART);

        vq_zero<<<16, 256, 0, stream>>>(counts, 4096);
        vq_pack2<<<1024, 256, 0, stream>>>(emb, bpk);
        vq_e2<<<K, 64, 0, stream>>>(emb, e2);
        vq_argmin10<<<(N / 256) * 2, 512, 0, stream>>>(z, (const char*)bpk, e2, part);
        vq_final2h<<<N / 4, 256, 0, stream>>>(part, emb, idxf, zq, counts, N);
        vq_ppl<<<1, 256, 0, stream>>>(counts, 1.0f / (float)N, ppl, K);
    } else {
        float* e2     = (float*)d_ws;
        int*   counts = (int*)((char*)d_ws + (size_t)K * sizeof(float));
        vq_e2<<<K, 64, 0, stream>>>(emb, e2);
        vq_zero<<<(K + 255) / 256, 256, 0, stream>>>(counts, K);
        vq_argmin_f32<<<N / 64, 256, 0, stream>>>(z, emb, e2, idxf, K);
        vq_gather<<<N / 4, 256, 0, stream>>>(emb, idxf, zq, N);
        vq_hist<<<(N + 255) / 256, 256, 0, stream>>>(idxf, counts, N);
        vq_ppl<<<1, 256, 0, stream>>>(counts, 1.0f / (float)N, ppl, K);
    }
}

// Round 18
// 222.275 us; speedup vs baseline: 1.4226x; 1.2784x over previous
//
#include <hip/hip_runtime.h>
#include <hip/hip_bf16.h>
#include <math.h>
#include <stdint.h>

typedef _Float16 f16;
typedef _Float16 f16x8 __attribute__((ext_vector_type(8)));
typedef float f32x16 __attribute__((ext_vector_type(16)));
typedef unsigned long long ull;

#define DIM 256
#define LOSCALE 2048.0f
#define INV_LOSCALE (1.0f/2048.0f)

// B' stream: 4096 codes x 256 depth x {hi,lo}, fragment-major:
// byte offset = col*32768 + s*2048 + t*1024 + lane*16
// (col 0..127 = 32 codes each, k-step s 0..15, t 0:hi 1:lo)
// lane l holds 16B = e[code=col*32+(l&31)][depth=s*16+(l>>5)*8 .. +8]
// 96KB pad: staging runs 2 cols past each half's end.
#define BP_BYTES (4096u*1024u + 98304u)

#define GLOAD16(gp, lp) __builtin_amdgcn_global_load_lds( \
    (const __attribute__((address_space(1))) void*)(gp),  \
    (__attribute__((address_space(3))) void*)(lp), 16, 0, 0)

// ---------------------------------------------------------------------------
// pack codebook into fragment-major hi/lo f16 stream
// ---------------------------------------------------------------------------
__global__ void vq_pack2(const float* __restrict__ emb, f16* __restrict__ bp)
{
    int o = blockIdx.x * blockDim.x + threadIdx.x;   // one per 16B chunk, 262144
    int l = o & 63;
    int b = o >> 6;
    int t   = b & 1;
    int s   = (b >> 1) & 15;
    int col = b >> 5;
    int code  = col * 32 + (l & 31);
    int depth = s * 16 + (l >> 5) * 8;
    const float* gp = emb + (size_t)code * DIM + depth;
    float4 x0 = *(const float4*)gp;
    float4 x1 = *(const float4*)(gp + 4);
    float xs[8] = {x0.x, x0.y, x0.z, x0.w, x1.x, x1.y, x1.z, x1.w};
    f16x8 v;
    #pragma unroll
    for (int j = 0; j < 8; ++j) {
        f16 h = (f16)xs[j];
        v[j] = t ? (f16)((xs[j] - (float)h) * LOSCALE) : h;
    }
    *(f16x8*)(bp + (size_t)o * 8) = v;
}

// merged: zero counts[k] + exact ||e_k||^2; one 64-thread block per code
__global__ void vq_e2z(const float* __restrict__ emb, float* __restrict__ e2,
                       int* __restrict__ counts) {
    int k = blockIdx.x;
    int l = threadIdx.x;
    float4 v = ((const float4*)(emb + (size_t)k * DIM))[l];
    float s = v.x * v.x + v.y * v.y + v.z * v.z + v.w * v.w;
    #pragma unroll
    for (int off = 32; off; off >>= 1) s += __shfl_xor(s, off);
    if (l == 0) { e2[k] = s; counts[k] = 0; }
}

// plain e2 + zero (fallback paths)
__global__ void vq_e2(const float* __restrict__ emb, float* __restrict__ e2) {
    int k = blockIdx.x;
    int l = threadIdx.x;
    float4 v = ((const float4*)(emb + (size_t)k * DIM))[l];
    float s = v.x*v.x + v.y*v.y + v.z*v.z + v.w*v.w;
    #pragma unroll
    for (int off = 32; off; off >>= 1) s += __shfl_xor(s, off);
    if (l == 0) e2[k] = s;
}

__global__ void vq_zero(int* __restrict__ p, int n) {
    int i = blockIdx.x * blockDim.x + threadIdx.x;
    if (i < n) p[i] = 0;
}

// ---------------------------------------------------------------------------
// MFMA argmin (r10, proven 195.6us): full-col units, 1 barrier per col,
// 512 thr = 8 waves x 32 rows = 256 rows/block, one code half (64 cols).
// 2 waves/SIMD. 4 x 32KB LDS buffers, counted vmcnt(8), raw s_barrier.
// Per col per wave: 32 ds_read_b128 -> 48 MFMA (3 indep chains).
// ---------------------------------------------------------------------------
__global__ __launch_bounds__(512, 2) void vq_argmin10(
    const float* __restrict__ z, const char* __restrict__ bp,
    const float* __restrict__ e2, ull* __restrict__ part)
{
    __shared__ __align__(16) char bufs[4][32768];   // 128 KB
    __shared__ float e2s[2048];                     // 8 KB

    const int t    = threadIdx.x;
    const int lane = t & 63;
    const int wv   = t >> 6;               // wave 0..7
    const int hw   = blockIdx.x & 1;       // code half
    const int rg   = blockIdx.x >> 1;      // row group (256 rows)
    const int l31  = lane & 31;
    const int hi5  = lane >> 5;
    const int rowbase = rg * 256 + wv * 32;

    // ---- e2 half to LDS ----
    *(float4*)&e2s[t * 4] = *(const float4*)(e2 + hw * 2048 + t * 4);

    // ---- A panel (32 rows) to registers, hi/lo split ----
    f16x8 a_h[16], a_l[16];
    {
        const float* zr = z + (size_t)(rowbase + l31) * DIM + hi5 * 8;
        #pragma unroll
        for (int s = 0; s < 16; ++s) {
            float4 x0 = *(const float4*)(zr + s * 16);
            float4 x1 = *(const float4*)(zr + s * 16 + 4);
            float xs[8] = {x0.x, x0.y, x0.z, x0.w, x1.x, x1.y, x1.z, x1.w};
            #pragma unroll
            for (int j = 0; j < 8; ++j) {
                f16 h = (f16)xs[j];
                a_h[s][j] = h;
                a_l[s][j] = (f16)((xs[j] - (float)h) * LOSCALE);
            }
        }
    }

    const char* bhalf = bp + ((size_t)hw << 21);   // 2 MB half

    // stage col cc (32KB) into buffer pb: 512 thr x 4 x 16B, linear
#define STAGE(pb, cc) do {                                                    \
    const char* src_ = bhalf + ((size_t)(cc) << 15) + (size_t)t * 16;         \
    char* dst_ = bufs[pb] + t * 16;                                           \
    _Pragma("unroll")                                                         \
    for (int i_ = 0; i_ < 4; ++i_)                                            \
        GLOAD16(src_ + i_ * 8192, dst_ + i_ * 8192);                          \
    } while (0)

    STAGE(0, 0);
    STAGE(1, 1);
    __syncthreads();   // full drain once: cols 0,1 staged; e2s visible

    float    bestd[16];
    unsigned bcol[4];
    #pragma unroll
    for (int q = 0; q < 16; ++q) bestd[q] = 3.4e38f;
    #pragma unroll
    for (int i = 0; i < 4; ++i) bcol[i] = 0u;

    for (int c = 0; c < 64; ++c) {
        // stage col c+2 into the buffer last read at col c-2 (race-free:
        // every wave passed barrier c-1, which implies compute(c-2) done)
        STAGE((c + 2) & 3, c + 2);

        asm volatile("s_waitcnt vmcnt(8)" ::: "memory");   // col c's 4 done
        asm volatile("s_waitcnt lgkmcnt(0)" ::: "memory");
        __builtin_amdgcn_s_barrier();
        __builtin_amdgcn_sched_barrier(0);

        f32x16 acc0, acc1a, acc1b;
        #pragma unroll
        for (int q = 0; q < 16; ++q) { acc0[q] = 0.0f; acc1a[q] = 0.0f; acc1b[q] = 0.0f; }

        const char* bb = bufs[c & 3];
        f16x8 bh_ = *(const f16x8*)(bb + lane * 16);
        f16x8 bl_ = *(const f16x8*)(bb + 1024 + lane * 16);
        __builtin_amdgcn_s_setprio(1);
        #pragma unroll
        for (int ks = 0; ks < 16; ++ks) {
            f16x8 bhn_, bln_;
            if (ks < 15) {
                bhn_ = *(const f16x8*)(bb + (ks + 1) * 2048 + lane * 16);
                bln_ = *(const f16x8*)(bb + (ks + 1) * 2048 + 1024 + lane * 16);
            }
            acc0  = __builtin_amdgcn_mfma_f32_32x32x16_f16(a_h[ks], bh_, acc0,  0, 0, 0);
            acc1a = __builtin_amdgcn_mfma_f32_32x32x16_f16(a_h[ks], bl_, acc1a, 0, 0, 0);
            acc1b = __builtin_amdgcn_mfma_f32_32x32x16_f16(a_l[ks], bh_, acc1b, 0, 0, 0);
            if (ks < 15) { bh_ = bhn_; bl_ = bln_; }
        }
        __builtin_amdgcn_s_setprio(0);

        // epilogue: fold scales, distances, running argmin
        float e2c = e2s[c * 32 + l31];
        #pragma unroll
        for (int q = 0; q < 16; ++q) {
            float dot  = fmaf(acc1a[q] + acc1b[q], INV_LOSCALE, acc0[q]);
            float dist = fmaf(-2.0f, dot, e2c);
            bool  lt   = dist < bestd[q];
            bestd[q]   = lt ? dist : bestd[q];
            const unsigned sh = (unsigned)((q & 3) * 8);
            unsigned nv = (bcol[q >> 2] & ~(0xFFu << sh)) | ((unsigned)c << sh);
            bcol[q >> 2] = lt ? nv : bcol[q >> 2];
        }
    }
#undef STAGE

    // ---- per-wave reduce across 32 code-lanes; write partial keys ----
    #pragma unroll
    for (int q = 0; q < 16; ++q) {
        float    d = bestd[q];
        unsigned c = (unsigned)(hw * 2048) +
                     ((bcol[q >> 2] >> ((q & 3) * 8)) & 0xFFu) * 32u + (unsigned)l31;
        #pragma unroll
        for (int o2 = 16; o2; o2 >>= 1) {
            float    od = __shfl_xor(d, o2);
            unsigned oc = __shfl_xor(c, o2);
            if (od < d || (od == d && oc < c)) { d = od; c = oc; }
        }
        if (l31 == 0) {
            int row = (q & 3) + 8 * (q >> 2) + 4 * hi5;
            unsigned u_  = __float_as_uint(d);
            unsigned key = u_ ^ (unsigned)(((int)u_ >> 31) | 0x80000000);
            part[(size_t)hw * 32768 + rowbase + row] = ((ull)key << 32) | c;
        }
    }
}

// fused: combine half-K partials -> idx, gather z_q row, histogram
__global__ void vq_final(const ull* __restrict__ part, const float* __restrict__ emb,
                         float* __restrict__ idxf, float* __restrict__ zq,
                         int* __restrict__ counts, int N)
{
    int n = blockIdx.x * 4 + (threadIdx.x >> 6);
    int l = threadIdx.x & 63;
    if (n >= N) return;
    ull a = part[n];
    ull b = part[(size_t)N + n];
    ull m = b < a ? b : a;
    int idx = (int)(unsigned)(m & 0xffffffffu) & 4095;
    ((float4*)(zq + (size_t)n * DIM))[l] =
        ((const float4*)(emb + (size_t)idx * DIM))[l];
    if (l == 0) {
        idxf[n] = (float)idx;
        atomicAdd(&counts[idx], 1);
    }
}

// ------------------------- low fallback (fp32 VALU) ------------------------
__global__ __launch_bounds__(256, 2) void vq_argmin_f32(
    const float* __restrict__ z, const float* __restrict__ emb,
    const float* __restrict__ e2, float* __restrict__ idxf, int K)
{
    __shared__ float zs[64 * 36];
    __shared__ float es[128 * 36];
    const int t = threadIdx.x;
    const int tx = t & 15;
    const int ty = t >> 4;
    const int rowbase = blockIdx.x * 64;
    const float* zbase = z + (size_t)rowbase * DIM;
    float best[4]; int bidx[4];
    #pragma unroll
    for (int i = 0; i < 4; ++i) { best[i] = 3.4e38f; bidx[i] = 0; }
    for (int kt = 0; kt < K; kt += 128) {
        float acc[4][8];
        #pragma unroll
        for (int i = 0; i < 4; ++i)
            #pragma unroll
            for (int j = 0; j < 8; ++j) acc[i][j] = 0.0f;
        for (int dc = 0; dc < DIM; dc += 32) {
            { int lr = t >> 2, o = (t & 3) * 8;
              const float* gp = zbase + (size_t)lr * DIM + dc + o;
              *(float4*)&zs[lr*36+o]   = *(const float4*)gp;
              *(float4*)&zs[lr*36+o+4] = *(const float4*)(gp+4); }
            { int lc = t >> 1, o = (t & 1) * 16;
              const float* gp = emb + (size_t)(kt+lc) * DIM + dc + o;
              *(float4*)&es[lc*36+o]    = *(const float4*)gp;
              *(float4*)&es[lc*36+o+4]  = *(const float4*)(gp+4);
              *(float4*)&es[lc*36+o+8]  = *(const float4*)(gp+8);
              *(float4*)&es[lc*36+o+12] = *(const float4*)(gp+12); }
            __syncthreads();
            const float* zp = &zs[(ty*4)*36];
            const float* ep = &es[tx*36];
            #pragma unroll
            for (int d = 0; d < 32; d += 4) {
                float4 zv[4], ev[8];
                #pragma unroll
                for (int i = 0; i < 4; ++i) zv[i] = *(const float4*)&zp[i*36+d];
                #pragma unroll
                for (int j = 0; j < 8; ++j) ev[j] = *(const float4*)&ep[j*16*36+d];
                #pragma unroll
                for (int i = 0; i < 4; ++i)
                    #pragma unroll
                    for (int j = 0; j < 8; ++j) {
                        acc[i][j] += zv[i].x*ev[j].x; acc[i][j] += zv[i].y*ev[j].y;
                        acc[i][j] += zv[i].z*ev[j].z; acc[i][j] += zv[i].w*ev[j].w;
                    }
            }
            __syncthreads();
        }
        #pragma unroll
        for (int j = 0; j < 8; ++j) {
            int c = kt + tx + 16*j;
            float ev2 = e2[c];
            #pragma unroll
            for (int i = 0; i < 4; ++i) {
                float dist = ev2 - 2.0f*acc[i][j];
                if (dist < best[i] || (dist == best[i] && c < bidx[i])) { best[i]=dist; bidx[i]=c; }
            }
        }
    }
    #pragma unroll
    for (int i = 0; i < 4; ++i) {
        float bd = best[i]; int bi = bidx[i];
        #pragma unroll
        for (int off = 8; off; off >>= 1) {
            float od = __shfl_xor(bd, off); int oi = __shfl_xor(bi, off);
            if (od < bd || (od == bd && oi < bi)) { bd = od; bi = oi; }
        }
        if (tx == 0) idxf[rowbase + ty*4 + i] = (float)bi;
    }
}

__global__ void vq_gather(const float* __restrict__ emb,
                          const float* __restrict__ idxf,
                          float* __restrict__ zq, int N)
{
    int n = blockIdx.x * 4 + (threadIdx.x >> 6);
    int l = threadIdx.x & 63;
    if (n >= N) return;
    int idx = (int)idxf[n];
    ((float4*)(zq + (size_t)n * DIM))[l] = ((const float4*)(emb + (size_t)idx * DIM))[l];
}

__global__ void vq_hist(const float* __restrict__ idxf, int* __restrict__ counts, int N) {
    int n = blockIdx.x * blockDim.x + threadIdx.x;
    if (n < N) atomicAdd(&counts[(int)idxf[n]], 1);
}

__global__ void vq_ppl(const int* __restrict__ counts, float invN,
                       float* __restrict__ out, int K)
{
    int t = threadIdx.x;
    float s = 0.0f;
    for (int k = t; k < K; k += 256) {
        float p = (float)counts[k] * invN;
        s += p * logf(p + 1e-10f);
    }
    #pragma unroll
    for (int off = 32; off; off >>= 1) s += __shfl_xor(s, off);
    __shared__ float wsum[4];
    if ((t & 63) == 0) wsum[t >> 6] = s;
    __syncthreads();
    if (t == 0) out[0] = expf(-(wsum[0] + wsum[1] + wsum[2] + wsum[3]));
}

extern "C" void kernel_launch(void* const* d_in, const int* in_sizes, int n_in,
                              void* d_out, int out_size, void* d_ws, size_t ws_size,
                              hipStream_t stream)
{
    const float* z   = (const float*)d_in[0];
    const float* emb = (const float*)d_in[1];
    const int N = in_sizes[0] / DIM;   // 32768
    const int K = in_sizes[1] / DIM;   // 4096

    float* out  = (float*)d_out;
    float* zq   = out;
    float* idxf = out + (size_t)N * DIM;
    float* ppl  = idxf + N;

    const size_t PART_BYTES = 2ull * 32768 * sizeof(ull);  // 512 KB
    const size_t NEED = (size_t)BP_BYTES + 16384 + 16384 + PART_BYTES;

    if (ws_size >= NEED && K == 4096 && N == 32768) {
        f16*   bpk    = (f16*)d_ws;
        float* e2     = (float*)((char*)d_ws + BP_BYTES);
        int*   counts = (int*)((char*)d_ws + BP_BYTES + 16384);
        ull*   part   = (ull*)((char*)d_ws + BP_BYTES + 32768);

        vq_pack2<<<1024, 256, 0, stream>>>(emb, bpk);
        vq_e2z<<<K, 64, 0, stream>>>(emb, e2, counts);
        vq_argmin10<<<(N / 256) * 2, 512, 0, stream>>>(z, (const char*)bpk, e2, part);
        vq_final<<<N / 4, 256, 0, stream>>>(part, emb, idxf, zq, counts, N);
        vq_ppl<<<1, 256, 0, stream>>>(counts, 1.0f / (float)N, ppl, K);
    } else {
        float* e2     = (float*)d_ws;
        int*   counts = (int*)((char*)d_ws + (size_t)K * sizeof(float));
        vq_e2<<<K, 64, 0, stream>>>(emb, e2);
        vq_zero<<<(K + 255) / 256, 256, 0, stream>>>(counts, K);
        vq_argmin_f32<<<N / 64, 256, 0, stream>>>(z, emb, e2, idxf, K);
        vq_gather<<<N / 4, 256, 0, stream>>>(emb, idxf, zq, N);
        vq_hist<<<(N + 255) / 256, 256, 0, stream>>>(idxf, counts, N);
        vq_ppl<<<1, 256, 0, stream>>>(counts, 1.0f / (float)N, ppl, K);
    }
}